// Round 10
// baseline (216.045 us; speedup 1.0000x reference)
//
#include <hip/hip_runtime.h>

// ---------------------------------------------------------------------------
// Linformer self-attention, fp32 I/O, fp16 MFMA internally, MI355X (gfx950)
// b=4 n=4096 d=1024 h=16 dh=64 k=256  (no 1/sqrt(dh) scale per reference)
//
// Key algebra: proj_k^T (X Wk) == (proj_k^T X) Wk  -> K/V paths cost 4x less.
// stage1 v4: 16-way n-split (z = c*4+b, 64 z) x 16 dd-tiles = 1024 blocks;
// block = 256 kk x 64 dd, 8 iters. f16 partials live in d_out (exact fit,
// overwritten later by attn). X fetched exactly once.
// ---------------------------------------------------------------------------

typedef __fp16 f16x8 __attribute__((ext_vector_type(8)));
typedef __fp16 f16x2 __attribute__((ext_vector_type(2)));
typedef float fl4 __attribute__((ext_vector_type(4)));
typedef float f32x4 __attribute__((ext_vector_type(4)));
typedef unsigned int u32x2 __attribute__((ext_vector_type(2)));
typedef unsigned int u32x4 __attribute__((ext_vector_type(4)));

#define MFMA16(a, b, c) __builtin_amdgcn_mfma_f32_16x16x32_f16((a), (b), (c), 0, 0, 0)

__device__ __forceinline__ unsigned int pk2u(float a, float b) {
  f16x2 p = __builtin_amdgcn_cvt_pkrtz(a, b);  // low = a, high = b
  return __builtin_bit_cast(unsigned int, p);
}

__device__ __forceinline__ f16x8 pk8(fl4 a, fl4 b) {
  f16x2 p0 = __builtin_amdgcn_cvt_pkrtz(a[0], a[1]);
  f16x2 p1 = __builtin_amdgcn_cvt_pkrtz(a[2], a[3]);
  f16x2 p2 = __builtin_amdgcn_cvt_pkrtz(b[0], b[1]);
  f16x2 p3 = __builtin_amdgcn_cvt_pkrtz(b[2], b[3]);
  f16x8 r;
  r[0] = p0[0]; r[1] = p0[1]; r[2] = p1[0]; r[3] = p1[1];
  r[4] = p2[0]; r[5] = p2[1]; r[6] = p3[0]; r[7] = p3[1];
  return r;
}

__device__ __forceinline__ void gload_lds16(const __fp16* g, void* lds_base) {
  __builtin_amdgcn_global_load_lds(
      (const __attribute__((address_space(1))) void*)g,
      (__attribute__((address_space(3))) void*)lds_base, 16, 0, 0);
}

// read a swizzled 64B-row tile fragment: logical chunk lg of `row`
__device__ __forceinline__ f16x8 rd_swz(const __fp16* base, int row, int lg) {
  return *(const f16x8*)((const char*)base + row * 64 +
                         ((lg ^ ((row >> 1) & 3)) * 16));
}

// ---------------------------------------------------------------------------
// Transpose + convert: in f32 [R][C] -> out f16 [C][R]. 32x32 tiles.
// ---------------------------------------------------------------------------
__global__ __launch_bounds__(256) void tr_cvt(
    const float* __restrict__ in, __fp16* __restrict__ out, int R, int C) {
  __shared__ float tile[32][33];
  const int t = threadIdx.x;
  const int c0 = blockIdx.x * 32, r0 = blockIdx.y * 32;
  {
    const int r = t >> 3, cg = (t & 7) * 4;
    fl4 v = *(const fl4*)(in + (size_t)(r0 + r) * C + c0 + cg);
    tile[r][cg] = v[0]; tile[r][cg + 1] = v[1];
    tile[r][cg + 2] = v[2]; tile[r][cg + 3] = v[3];
  }
  __syncthreads();
  {
    const int cc = t >> 3, rg = (t & 7) * 4;
    u32x2 p;
    p[0] = pk2u(tile[rg + 0][cc], tile[rg + 1][cc]);
    p[1] = pk2u(tile[rg + 2][cc], tile[rg + 3][cc]);
    *(u32x2*)(out + (size_t)(c0 + cc) * R + r0 + rg) = p;
  }
}

// ---------------------------------------------------------------------------
// Stage 1 v4: Pk16[z][kk][dd] = sum_{n in 256-chunk c} pkT[kk][n]*X[b][n][dd]
// (z = c*4+b, c in [0,16)). Block = 256 kk x 64 dd; wave w = kk [w*64,+64).
// Grid (64 z, 16 dd): all dd-blocks of a z share an XCD (stride 64 = 0 mod 8)
// -> pkT/pvT slab L2-resident. 8 iters/block; 1024 blocks for latency hiding.
// ---------------------------------------------------------------------------
__global__ __launch_bounds__(256) void stage1_partial(
    const __fp16* __restrict__ pkT,  // [256][4096]
    const __fp16* __restrict__ pvT,  // [256][4096]
    const float* __restrict__ X,     // [b][4096][1024]
    __fp16* __restrict__ Pk,         // [64][256][1024] f16 partials (in d_out)
    __fp16* __restrict__ Pv) {       // [64][256][1024]
  __shared__ __fp16 Ak[256 * 32];  // 16KB, rows kk
  __shared__ __fp16 Av[256 * 32];  // 16KB
  __shared__ __fp16 Bt[64 * 32];   // 4KB, rows dd
  const int t = threadIdx.x;
  const int lane = t & 63, w = t >> 6;
  const int lr = lane & 15, lg = lane >> 4;
  const int z = blockIdx.x, b = z & 3, c = z >> 2;
  const int dd0 = blockIdx.y * 64;

  f32x4 acck[4][4], accv[4][4];
#pragma unroll
  for (int i = 0; i < 4; ++i)
#pragma unroll
    for (int j = 0; j < 4; ++j) {
      acck[i][j] = (f32x4){0.f, 0.f, 0.f, 0.f};
      accv[i][j] = (f32x4){0.f, 0.f, 0.f, 0.f};
    }

  // A gload: instruction i covers rows i*64 + w*16 + (lane>>2)
  const int arow = w * 16 + (lane >> 2);
  const int ach = (lane & 3) ^ ((lane >> 3) & 3);  // source chunk pre-swizzle
  const __fp16* pkSrc = pkT + (size_t)arow * 4096 + c * 256 + ach * 8;
  const __fp16* pvSrc = pvT + (size_t)arow * 4096 + c * 256 + ach * 8;
  // X staging: n-pair p = t>>4, dd-quad qd = t&15 (verified pattern)
  const int p = t >> 4, qd = t & 15;
  const int ppos = p ^ ((qd & 3) << 2);
  const float* xSrc =
      X + ((size_t)b * 4096 + c * 256 + 2 * p) * 1024 + dd0 + qd * 4;

  for (int it = 0; it < 8; ++it) {
    const int n0 = it * 32;
    fl4 x0 = *(const fl4*)(xSrc + (size_t)n0 * 1024);
    fl4 x1 = *(const fl4*)(xSrc + (size_t)n0 * 1024 + 1024);
    __syncthreads();
#pragma unroll
    for (int i = 0; i < 4; ++i) {
      gload_lds16(pkSrc + (size_t)i * 64 * 4096 + n0,
                  (char*)Ak + i * 4096 + w * 1024);
      gload_lds16(pvSrc + (size_t)i * 64 * 4096 + n0,
                  (char*)Av + i * 4096 + w * 1024);
    }
#pragma unroll
    for (int j = 0; j < 4; ++j)
      *(unsigned int*)((char*)Bt + (qd * 4 + j) * 64 + ppos * 4) =
          pk2u(x0[j], x1[j]);
    __syncthreads();

    f16x8 ak[4], av[4], bx[4];
#pragma unroll
    for (int i = 0; i < 4; ++i) {
      ak[i] = rd_swz(Ak, w * 64 + i * 16 + lr, lg);
      av[i] = rd_swz(Av, w * 64 + i * 16 + lr, lg);
    }
#pragma unroll
    for (int j = 0; j < 4; ++j) {
      const int dd = j * 16 + lr;
      bx[j] = *(const f16x8*)((const char*)Bt + dd * 64 +
                              ((lg ^ ((dd >> 2) & 3)) * 16));
    }
#pragma unroll
    for (int i = 0; i < 4; ++i)
#pragma unroll
      for (int j = 0; j < 4; ++j) {
        acck[i][j] = MFMA16(ak[i], bx[j], acck[i][j]);
        accv[i][j] = MFMA16(av[i], bx[j], accv[i][j]);
      }
  }

  __fp16* pkOut = Pk + (size_t)z * 256 * 1024;
  __fp16* pvOut = Pv + (size_t)z * 256 * 1024;
#pragma unroll
  for (int i = 0; i < 4; ++i)
#pragma unroll
    for (int j = 0; j < 4; ++j)
#pragma unroll
      for (int r = 0; r < 4; ++r) {
        const int row = w * 64 + i * 16 + lg * 4 + r;
        const int col = dd0 + j * 16 + lr;
        pkOut[(size_t)row * 1024 + col] = (__fp16)acck[i][j][r];
        pvOut[(size_t)row * 1024 + col] = (__fp16)accv[i][j][r];
      }
}

// ---------------------------------------------------------------------------
// Stage 1 reduce: Xk = f16(sum_{c<16} f32(Pk16[c*4+b])). 8 f16/thread.
// ---------------------------------------------------------------------------
__global__ __launch_bounds__(256) void stage1_reduce(
    const __fp16* __restrict__ Pk, const __fp16* __restrict__ Pv,
    __fp16* __restrict__ Xk, __fp16* __restrict__ Xv) {
  const size_t idx = ((size_t)blockIdx.x * 256 + threadIdx.x) * 8;
  const int b = (int)(idx >> 18);           // 262144 elems per batch slab
  const size_t rem = idx & 0x3FFFFu;
  float sk[8], sv[8];
#pragma unroll
  for (int j = 0; j < 8; ++j) { sk[j] = 0.f; sv[j] = 0.f; }
#pragma unroll
  for (int c = 0; c < 16; ++c) {
    const size_t off = (((size_t)(c * 4 + b)) << 18) + rem;
    f16x8 vk = *(const f16x8*)(Pk + off);
    f16x8 vv = *(const f16x8*)(Pv + off);
#pragma unroll
    for (int j = 0; j < 8; ++j) {
      sk[j] += (float)vk[j];
      sv[j] += (float)vv[j];
    }
  }
  f16x8 ok, ov;
#pragma unroll
  for (int j = 0; j < 8; ++j) {
    ok[j] = (__fp16)sk[j];
    ov[j] = (__fp16)sv[j];
  }
  *(f16x8*)(Xk + idx) = ok;
  *(f16x8*)(Xv + idx) = ov;
}

// ---------------------------------------------------------------------------
// Generic small BT-GEMM: C[i][j] (f16) = sum_e A[i][e] * B[j][e], E=1024.
// ---------------------------------------------------------------------------
__global__ __launch_bounds__(256) void bt64(
    const __fp16* __restrict__ A, long long bsA,
    const __fp16* __restrict__ B, long long bsB,
    __fp16* __restrict__ C, int ldC, long long bsC) {
  constexpr int E = 1024;
  __shared__ __fp16 As[64 * 32];
  __shared__ __fp16 Bs[64 * 32];
  const int t = threadIdx.x;
  const int lane = t & 63, w = t >> 6;
  const int lr = lane & 15, lg = lane >> 4;
  const int i0 = blockIdx.x * 64, j0 = blockIdx.y * 64;
  A += (size_t)blockIdx.z * (size_t)bsA;
  B += (size_t)blockIdx.z * (size_t)bsB;
  C += (size_t)blockIdx.z * (size_t)bsC;
  const int wr = (w >> 1) * 32, wc = (w & 1) * 32;

  f32x4 acc[2][2];
#pragma unroll
  for (int i = 0; i < 2; ++i)
#pragma unroll
    for (int j = 0; j < 2; ++j) acc[i][j] = (f32x4){0.f, 0.f, 0.f, 0.f};

  const int gl_row = w * 16 + (lane >> 2);
  const int gl_ch = (lane & 3) ^ ((lane >> 3) & 3);
  const __fp16* aSrc = A + (size_t)(i0 + gl_row) * E + gl_ch * 8;
  const __fp16* bSrc = B + (size_t)(j0 + gl_row) * E + gl_ch * 8;

  for (int e0 = 0; e0 < E; e0 += 32) {
    __syncthreads();
    gload_lds16(aSrc + e0, (char*)As + w * 1024);
    gload_lds16(bSrc + e0, (char*)Bs + w * 1024);
    __syncthreads();

    f16x8 af[2], bf[2];
#pragma unroll
    for (int i = 0; i < 2; ++i)
      af[i] = rd_swz(As, wr + i * 16 + lr, lg);
#pragma unroll
    for (int j = 0; j < 2; ++j)
      bf[j] = rd_swz(Bs, wc + j * 16 + lr, lg);
#pragma unroll
    for (int i = 0; i < 2; ++i)
#pragma unroll
      for (int j = 0; j < 2; ++j)
        acc[i][j] = MFMA16(af[i], bf[j], acc[i][j]);
  }

#pragma unroll
  for (int i = 0; i < 2; ++i)
#pragma unroll
    for (int j = 0; j < 2; ++j)
#pragma unroll
      for (int r = 0; r < 4; ++r) {
        const int row = i0 + wr + i * 16 + lg * 4 + r;
        const int col = j0 + wc + j * 16 + lr;
        C[(size_t)row * ldC + col] = (__fp16)acc[i][j][r];
      }
}

// ---------------------------------------------------------------------------
// Q-path GEMM: Qh[16384][1024] (f16) = X(f32) . WqT^T, 128x128 tile, BK=32.
// ---------------------------------------------------------------------------
__global__ __launch_bounds__(256) void gemm_q(
    const float* __restrict__ X,
    const __fp16* __restrict__ WT,   // [1024][1024], WT[n][k] = W[k][n]
    __fp16* __restrict__ Q) {
  constexpr int K = 1024, N = 1024;
  __shared__ __fp16 Xs[128 * 32];
  __shared__ __fp16 Ws[128 * 32];
  const int t = threadIdx.x;
  const int lane = t & 63, w = t >> 6;
  const int lr = lane & 15, lg = lane >> 4;
  const int m0 = blockIdx.x * 128, n0 = blockIdx.y * 128;
  const int wr = (w >> 1) * 64, wc = (w & 1) * 64;

  f32x4 acc[4][4];
#pragma unroll
  for (int i = 0; i < 4; ++i)
#pragma unroll
    for (int j = 0; j < 4; ++j) acc[i][j] = (f32x4){0.f, 0.f, 0.f, 0.f};

  const int xrow = t >> 2;
  const int xpos = (t & 3) ^ ((t >> 3) & 3);
  const float* xSrc1 = X + (size_t)(m0 + xrow) * K + (t & 3) * 8;
  const float* xSrc2 = xSrc1 + (size_t)64 * K;
  const int gl_row = w * 16 + (lane >> 2);
  const int gl_ch = (lane & 3) ^ ((lane >> 3) & 3);
  const __fp16* wSrc0 = WT + (size_t)(n0 + gl_row) * K + gl_ch * 8;
  const __fp16* wSrc1 = WT + (size_t)(n0 + 64 + gl_row) * K + gl_ch * 8;

  for (int k0 = 0; k0 < K; k0 += 32) {
    fl4 a0 = *(const fl4*)(xSrc1 + k0);
    fl4 a1 = *(const fl4*)(xSrc1 + k0 + 4);
    fl4 a2 = *(const fl4*)(xSrc2 + k0);
    fl4 a3 = *(const fl4*)(xSrc2 + k0 + 4);
    __syncthreads();
    gload_lds16(wSrc0 + k0, (char*)Ws + w * 1024);
    gload_lds16(wSrc1 + k0, (char*)Ws + 4096 + w * 1024);
    *(f16x8*)((char*)Xs + xrow * 64 + xpos * 16) = pk8(a0, a1);
    *(f16x8*)((char*)Xs + (64 + xrow) * 64 + xpos * 16) = pk8(a2, a3);
    __syncthreads();

    f16x8 af[4], bf[4];
#pragma unroll
    for (int i = 0; i < 4; ++i)
      af[i] = rd_swz(Xs, wr + i * 16 + lr, lg);
#pragma unroll
    for (int j = 0; j < 4; ++j)
      bf[j] = rd_swz(Ws, wc + j * 16 + lr, lg);
#pragma unroll
    for (int i = 0; i < 4; ++i)
#pragma unroll
      for (int j = 0; j < 4; ++j)
        acc[i][j] = MFMA16(af[i], bf[j], acc[i][j]);
  }

#pragma unroll
  for (int i = 0; i < 4; ++i)
#pragma unroll
    for (int j = 0; j < 4; ++j)
#pragma unroll
      for (int r = 0; r < 4; ++r) {
        const int row = m0 + wr + i * 16 + lg * 4 + r;
        const int col = n0 + wc + j * 16 + lr;
        Q[(size_t)row * N + col] = (__fp16)acc[i][j][r];
      }
}

// ---------------------------------------------------------------------------
// Attention v3: block = 4 waves, 128 Q-rows of one (b,h); grid 2048.
// 32KB LDS (K then V), swapped QK^T, in-register P via cvt_pk + ds_bpermute.
// ---------------------------------------------------------------------------
__global__ __launch_bounds__(256) void attn_k(
    const __fp16* __restrict__ Q,    // [b*4096][1024]
    const __fp16* __restrict__ Kp,   // [b][256][1024]
    const __fp16* __restrict__ Vpt,  // [b][1024][256]
    float* __restrict__ O) {         // [b*4096][1024] f32
  __shared__ __fp16 KV[256 * 64];    // 32KB: K tile, then V^T tile
  const int t = threadIdx.x;
  const int lane = t & 63, w = t >> 6;
  const int lr = lane & 15, lg = lane >> 4;
  const int bh = blockIdx.x >> 5, rb = blockIdx.x & 31;
  const int b = bh >> 4, h = bh & 15;
  const int m0 = rb * 128 + w * 32;

  const __fp16* Kph = Kp + (size_t)b * 256 * 1024 + h * 64;
  const __fp16* Vph = Vpt + ((size_t)b * 1024 + h * 64) * 256;
  const __fp16* Qh = Q + ((size_t)(b * 4096 + m0)) * 1024 + h * 64;

#pragma unroll
  for (int i = 0; i < 8; ++i) {
    const int kr = (i * 4 + w) * 8 + (lane >> 3);
    gload_lds16(Kph + (size_t)kr * 1024 + (((lane & 7) ^ (kr & 7)) * 8),
                (char*)KV + (i * 4 + w) * 1024);
  }

  f16x8 aq[2][2];
#pragma unroll
  for (int mi = 0; mi < 2; ++mi)
#pragma unroll
    for (int s = 0; s < 2; ++s)
      aq[mi][s] =
          *(const f16x8*)(Qh + (size_t)(mi * 16 + lr) * 1024 + s * 32 + lg * 8);

  __syncthreads();  // K staged

  f32x4 dots[2][16];
#pragma unroll
  for (int mi = 0; mi < 2; ++mi)
#pragma unroll
    for (int jt = 0; jt < 16; ++jt) dots[mi][jt] = (f32x4){0.f, 0.f, 0.f, 0.f};
#pragma unroll
  for (int jt = 0; jt < 16; ++jt) {
    const int r = jt * 16 + lr;
    f16x8 k0 = *(const f16x8*)((const char*)KV + r * 128 + ((lg ^ (r & 7)) * 16));
    f16x8 k1 =
        *(const f16x8*)((const char*)KV + r * 128 + (((4 + lg) ^ (r & 7)) * 16));
    dots[0][jt] = MFMA16(k0, aq[0][0], dots[0][jt]);
    dots[0][jt] = MFMA16(k1, aq[0][1], dots[0][jt]);
    dots[1][jt] = MFMA16(k0, aq[1][0], dots[1][jt]);
    dots[1][jt] = MFMA16(k1, aq[1][1], dots[1][jt]);
  }

  unsigned cpk[2][16][2];
  float smv[2];
#pragma unroll
  for (int mi = 0; mi < 2; ++mi) {
    float mx = -1e30f;
#pragma unroll
    for (int jt = 0; jt < 16; ++jt)
#pragma unroll
      for (int r = 0; r < 4; ++r) mx = fmaxf(mx, dots[mi][jt][r]);
    mx = fmaxf(mx, __shfl_xor(mx, 16, 64));
    mx = fmaxf(mx, __shfl_xor(mx, 32, 64));
    float sm = 0.f;
#pragma unroll
    for (int jt = 0; jt < 16; ++jt) {
#pragma unroll
      for (int r = 0; r < 4; ++r) {
        float p = __expf(dots[mi][jt][r] - mx);
        dots[mi][jt][r] = p;
        sm += p;
      }
      cpk[mi][jt][0] = pk2u(dots[mi][jt][0], dots[mi][jt][1]);
      cpk[mi][jt][1] = pk2u(dots[mi][jt][2], dots[mi][jt][3]);
    }
    sm += __shfl_xor(sm, 16, 64);
    sm += __shfl_xor(sm, 32, 64);
    smv[mi] = sm;
  }

  __syncthreads();  // all waves done reading K

#pragma unroll
  for (int i = 0; i < 8; ++i) {
    const int dd = (i * 4 + w) * 2 + (lane >> 5);
    gload_lds16(Vph + (size_t)dd * 256 + (((lane & 31) ^ (dd & 7)) * 8),
                (char*)KV + (i * 4 + w) * 1024);
  }
  __syncthreads();  // V staged

#pragma unroll
  for (int mi = 0; mi < 2; ++mi) {
    f32x4 o[4];
#pragma unroll
    for (int j = 0; j < 4; ++j) o[j] = (f32x4){0.f, 0.f, 0.f, 0.f};
#pragma unroll
    for (int ks = 0; ks < 8; ++ks) {
      u32x4 wds;
#pragma unroll
      for (int m = 0; m < 4; ++m) {
        const int addr = ((((lane & 16) >> 3) + (m >> 1)) * 16 + lr) * 4;
        const int a0 = __builtin_amdgcn_ds_bpermute(
            addr, (int)cpk[mi][ks * 2][m & 1]);
        const int a1 = __builtin_amdgcn_ds_bpermute(
            addr, (int)cpk[mi][ks * 2 + 1][m & 1]);
        wds[m] = (unsigned)((lg >> 1) ? a1 : a0);
      }
      f16x8 pa = __builtin_bit_cast(f16x8, wds);
#pragma unroll
      for (int jt2 = 0; jt2 < 4; ++jt2) {
        const int dd = jt2 * 16 + lr;
        f16x8 bv = *(const f16x8*)((const char*)KV + dd * 512 +
                                   (((ks * 4 + lg) ^ (dd & 7)) * 16));
        o[jt2] = MFMA16(pa, bv, o[jt2]);
      }
    }

    float rs[4];
#pragma unroll
    for (int r = 0; r < 4; ++r)
      rs[r] = 1.f / __shfl(smv[mi], (lane & 48) + lg * 4 + r, 64);
#pragma unroll
    for (int jt2 = 0; jt2 < 4; ++jt2)
#pragma unroll
      for (int r = 0; r < 4; ++r) {
        const size_t row = (size_t)(b * 4096 + m0 + mi * 16 + lg * 4 + r);
        O[row * 1024 + h * 64 + jt2 * 16 + lr] = o[jt2][r] * rs[r];
      }
  }
}

// ---------------------------------------------------------------------------
extern "C" void kernel_launch(void* const* d_in, const int* in_sizes, int n_in,
                              void* d_out, int out_size, void* d_ws, size_t ws_size,
                              hipStream_t stream) {
  (void)in_sizes; (void)n_in; (void)out_size; (void)ws_size;
  const float* x  = (const float*)d_in[0];
  const float* Wq = (const float*)d_in[1];
  const float* Wk = (const float*)d_in[2];
  const float* Wv = (const float*)d_in[3];
  const float* pk = (const float*)d_in[4];
  const float* pv = (const float*)d_in[5];
  float* out = (float*)d_out;

  // ws layout (f16 halfwords), ~52.4 MB. f16 partials (67.1 MB, exact fit)
  // live in d_out, which attn_k fully overwrites at the end.
  __fp16* Qh  = (__fp16*)d_ws;                       // 16384*1024 f16
  __fp16* WqT = Qh  + (size_t)16384 * 1024;          // 1024*1024 each
  __fp16* WkT = WqT + (size_t)1024 * 1024;
  __fp16* WvT = WkT + (size_t)1024 * 1024;
  __fp16* pkT = WvT + (size_t)1024 * 1024;           // 256*4096 each
  __fp16* pvT = pkT + (size_t)256 * 4096;
  __fp16* Xk  = pvT + (size_t)256 * 4096;            // 4*256*1024 each
  __fp16* Xv  = Xk  + (size_t)4 * 256 * 1024;
  __fp16* Kp  = Xv  + (size_t)4 * 256 * 1024;
  __fp16* Vpt = Kp  + (size_t)4 * 256 * 1024;
  __fp16* Pk16 = (__fp16*)d_out;                     // 64*256*1024 f16 each
  __fp16* Pv16 = Pk16 + (size_t)64 * 256 * 1024;

  const dim3 bb(256);

  // 0. one-time transposes (f32 -> f16)
  tr_cvt<<<dim3(32, 32), bb, 0, stream>>>(Wq, WqT, 1024, 1024);
  tr_cvt<<<dim3(32, 32), bb, 0, stream>>>(Wk, WkT, 1024, 1024);
  tr_cvt<<<dim3(32, 32), bb, 0, stream>>>(Wv, WvT, 1024, 1024);
  tr_cvt<<<dim3(8, 128), bb, 0, stream>>>(pk, pkT, 4096, 256);
  tr_cvt<<<dim3(8, 128), bb, 0, stream>>>(pv, pvT, 4096, 256);

  // 1. split-K low-rank projections of X + reduce (partials in d_out)
  stage1_partial<<<dim3(64, 16), bb, 0, stream>>>(pkT, pvT, x, Pk16, Pv16);
  stage1_reduce<<<dim3(512), bb, 0, stream>>>(Pk16, Pv16, Xk, Xv);

  // 2. Kp = Xk . Wk ; VpT = (Xv . Wv)^T
  bt64<<<dim3(4, 16, 4), bb, 0, stream>>>(Xk, 256LL * 1024, WkT, 0LL,
                                          Kp, 1024, 256LL * 1024);
  bt64<<<dim3(16, 4, 4), bb, 0, stream>>>(WvT, 0LL, Xv, 256LL * 1024,
                                          Vpt, 256, 1024LL * 256);

  // 3. Q projection
  gemm_q<<<dim3(128, 8), bb, 0, stream>>>(x, WqT, Qh);

  // 4. attention (overwrites the partials region = d_out)
  attn_k<<<dim3(2048), bb, 0, stream>>>(Qh, Kp, Vpt, out);
}

// Round 11
// 197.083 us; speedup vs baseline: 1.0962x; 1.0962x over previous
//
#include <hip/hip_runtime.h>

// ---------------------------------------------------------------------------
// Linformer self-attention, fp32 I/O, fp16 MFMA internally, MI355X (gfx950)
// b=4 n=4096 d=1024 h=16 dh=64 k=256  (no 1/sqrt(dh) scale per reference)
//
// Key algebra: proj_k^T (X Wk) == (proj_k^T X) Wk  -> K/V paths cost 4x less.
// This round: software-pipelined staging (issue-early / drain-under-compute)
// in stage1 + gemm_q, double-buffered LDS, XCD co-scheduling block swizzle.
// ---------------------------------------------------------------------------

typedef __fp16 f16x8 __attribute__((ext_vector_type(8)));
typedef __fp16 f16x2 __attribute__((ext_vector_type(2)));
typedef float fl4 __attribute__((ext_vector_type(4)));
typedef float f32x4 __attribute__((ext_vector_type(4)));
typedef unsigned int u32x2 __attribute__((ext_vector_type(2)));
typedef unsigned int u32x4 __attribute__((ext_vector_type(4)));

#define MFMA16(a, b, c) __builtin_amdgcn_mfma_f32_16x16x32_f16((a), (b), (c), 0, 0, 0)

__device__ __forceinline__ unsigned int pk2u(float a, float b) {
  f16x2 p = __builtin_amdgcn_cvt_pkrtz(a, b);  // low = a, high = b
  return __builtin_bit_cast(unsigned int, p);
}

__device__ __forceinline__ f16x8 pk8(fl4 a, fl4 b) {
  f16x2 p0 = __builtin_amdgcn_cvt_pkrtz(a[0], a[1]);
  f16x2 p1 = __builtin_amdgcn_cvt_pkrtz(a[2], a[3]);
  f16x2 p2 = __builtin_amdgcn_cvt_pkrtz(b[0], b[1]);
  f16x2 p3 = __builtin_amdgcn_cvt_pkrtz(b[2], b[3]);
  f16x8 r;
  r[0] = p0[0]; r[1] = p0[1]; r[2] = p1[0]; r[3] = p1[1];
  r[4] = p2[0]; r[5] = p2[1]; r[6] = p3[0]; r[7] = p3[1];
  return r;
}

__device__ __forceinline__ void gload_lds16(const __fp16* g, void* lds_base) {
  __builtin_amdgcn_global_load_lds(
      (const __attribute__((address_space(1))) void*)g,
      (__attribute__((address_space(3))) void*)lds_base, 16, 0, 0);
}

// read a swizzled 64B-row tile fragment: logical chunk lg of `row`
__device__ __forceinline__ f16x8 rd_swz(const __fp16* base, int row, int lg) {
  return *(const f16x8*)((const char*)base + row * 64 +
                         ((lg ^ ((row >> 1) & 3)) * 16));
}

// ---------------------------------------------------------------------------
// Transpose + convert: in f32 [R][C] -> out f16 [C][R]. 32x32 tiles.
// ---------------------------------------------------------------------------
__global__ __launch_bounds__(256) void tr_cvt(
    const float* __restrict__ in, __fp16* __restrict__ out, int R, int C) {
  __shared__ float tile[32][33];
  const int t = threadIdx.x;
  const int c0 = blockIdx.x * 32, r0 = blockIdx.y * 32;
  {
    const int r = t >> 3, cg = (t & 7) * 4;
    fl4 v = *(const fl4*)(in + (size_t)(r0 + r) * C + c0 + cg);
    tile[r][cg] = v[0]; tile[r][cg + 1] = v[1];
    tile[r][cg + 2] = v[2]; tile[r][cg + 3] = v[3];
  }
  __syncthreads();
  {
    const int cc = t >> 3, rg = (t & 7) * 4;
    u32x2 p;
    p[0] = pk2u(tile[rg + 0][cc], tile[rg + 1][cc]);
    p[1] = pk2u(tile[rg + 2][cc], tile[rg + 3][cc]);
    *(u32x2*)(out + (size_t)(c0 + cc) * R + r0 + rg) = p;
  }
}

// ---------------------------------------------------------------------------
// Stage 1 v5: Pk[z][kk][dd] = sum_{n in 1024-chunk c} pkT[kk][n]*X[b][n][dd]
// (z = c*4+b). Tile 64kk x 64dd, BK=32, 32 iters. DOUBLE-BUFFERED pipeline:
// issue next-iter gload/X-loads -> compute current -> sync (drain hides
// under compute) -> write Bt[nxt] -> sync. XCD swizzle: the 4 kk-blocks of
// one (dd,z) at flat ids {g*32 + kk*8 + p} -> same XCD -> X L2-shared.
// ---------------------------------------------------------------------------
__global__ __launch_bounds__(256) void stage1_partial(
    const __fp16* __restrict__ pkT,  // [256][4096]
    const __fp16* __restrict__ pvT,  // [256][4096]
    const float* __restrict__ X,     // [b][4096][1024]
    float* __restrict__ Pk,          // [16][256][1024] f32 partials
    float* __restrict__ Pv) {        // [16][256][1024]
  __shared__ __fp16 Ak[2][64 * 32];
  __shared__ __fp16 Av[2][64 * 32];
  __shared__ __fp16 Bt[2][64 * 32];
  const int t = threadIdx.x;
  const int lane = t & 63, w = t >> 6;
  const int lr = lane & 15, lg = lane >> 4;
  // XCD co-scheduling decode: fid = g*32 + kk*8 + p ; (dd,z) = g*8+p
  const int fid = blockIdx.x;
  const int g = fid >> 5, s = fid & 31;
  const int kk = s >> 3, p8 = s & 7;
  const int pr = g * 8 + p8;
  const int kk0 = kk * 64, dd0 = (pr & 15) * 64;
  const int z = pr >> 4, b = z & 3, c = z >> 2;
  const int wr = (w >> 1) * 32, wc = (w & 1) * 32;

  f32x4 acck[2][2], accv[2][2];
#pragma unroll
  for (int i = 0; i < 2; ++i)
#pragma unroll
    for (int j = 0; j < 2; ++j) {
      acck[i][j] = (f32x4){0.f, 0.f, 0.f, 0.f};
      accv[i][j] = (f32x4){0.f, 0.f, 0.f, 0.f};
    }

  const int gl_row = w * 16 + (lane >> 2);
  const int gl_ch = (lane & 3) ^ ((lane >> 3) & 3);
  const __fp16* pkSrc = pkT + (size_t)(kk0 + gl_row) * 4096 + c * 1024 + gl_ch * 8;
  const __fp16* pvSrc = pvT + (size_t)(kk0 + gl_row) * 4096 + c * 1024 + gl_ch * 8;
  const int pp = t >> 4, qd = t & 15;
  const int ppos = pp ^ ((qd & 3) << 2);
  const float* xSrc =
      X + ((size_t)b * 4096 + c * 1024 + 2 * pp) * 1024 + dd0 + qd * 4;

  // ---- prologue: stage iter 0 into buffer 0
  gload_lds16(pkSrc, (char*)Ak[0] + w * 1024);
  gload_lds16(pvSrc, (char*)Av[0] + w * 1024);
  fl4 x0 = *(const fl4*)(xSrc);
  fl4 x1 = *(const fl4*)(xSrc + 1024);
  __syncthreads();
#pragma unroll
  for (int j = 0; j < 4; ++j)
    *(unsigned int*)((char*)Bt[0] + (qd * 4 + j) * 64 + ppos * 4) =
        pk2u(x0[j], x1[j]);
  __syncthreads();

  for (int it = 0; it < 32; ++it) {
    const int cur = it & 1, nxt = cur ^ 1;
    if (it < 31) {
      const int n1 = (it + 1) * 32;
      gload_lds16(pkSrc + n1, (char*)Ak[nxt] + w * 1024);
      gload_lds16(pvSrc + n1, (char*)Av[nxt] + w * 1024);
      x0 = *(const fl4*)(xSrc + (size_t)n1 * 1024);
      x1 = *(const fl4*)(xSrc + (size_t)n1 * 1024 + 1024);
    }
    // compute current tile (drain of prefetch happens at the sync below)
    f16x8 ak[2], av[2], bx[2];
#pragma unroll
    for (int i = 0; i < 2; ++i) {
      ak[i] = rd_swz(Ak[cur], wr + i * 16 + lr, lg);
      av[i] = rd_swz(Av[cur], wr + i * 16 + lr, lg);
    }
#pragma unroll
    for (int j = 0; j < 2; ++j) {
      const int dd = wc + j * 16 + lr;
      bx[j] = *(const f16x8*)((const char*)Bt[cur] + dd * 64 +
                              ((lg ^ ((dd >> 2) & 3)) * 16));
    }
#pragma unroll
    for (int i = 0; i < 2; ++i)
#pragma unroll
      for (int j = 0; j < 2; ++j) {
        acck[i][j] = MFMA16(ak[i], bx[j], acck[i][j]);
        accv[i][j] = MFMA16(av[i], bx[j], accv[i][j]);
      }
    __syncthreads();  // prefetch landed during compute; cur readers done
    if (it < 31) {
#pragma unroll
      for (int j = 0; j < 4; ++j)
        *(unsigned int*)((char*)Bt[nxt] + (qd * 4 + j) * 64 + ppos * 4) =
            pk2u(x0[j], x1[j]);
    }
    __syncthreads();  // Bt[nxt] visible
  }

#pragma unroll
  for (int i = 0; i < 2; ++i)
#pragma unroll
    for (int j = 0; j < 2; ++j)
#pragma unroll
      for (int r = 0; r < 4; ++r) {
        const size_t row = (size_t)z * 256 + kk0 + wr + i * 16 + lg * 4 + r;
        const int col = dd0 + wc + j * 16 + lr;
        Pk[row * 1024 + col] = acck[i][j][r];
        Pv[row * 1024 + col] = accv[i][j][r];
      }
}

// ---------------------------------------------------------------------------
// Stage 1 reduce: Xk = f16(sum_c Pk[c*4+b]), Xv likewise. 4 f32/thread.
// ---------------------------------------------------------------------------
__global__ __launch_bounds__(256) void stage1_reduce(
    const float* __restrict__ Pk, const float* __restrict__ Pv,
    __fp16* __restrict__ Xk, __fp16* __restrict__ Xv) {
  const size_t base = ((size_t)blockIdx.x * 256 + threadIdx.x) * 4;
  const int b = (int)(base >> 18);          // 256K elems per batch slab
  const size_t rem = base & 0x3FFFFu;
  fl4 ak = (fl4){0.f, 0.f, 0.f, 0.f}, av = (fl4){0.f, 0.f, 0.f, 0.f};
#pragma unroll
  for (int c = 0; c < 4; ++c) {
    const size_t off = (((size_t)(c * 4 + b)) << 18) + rem;
    ak += *(const fl4*)(Pk + off);
    av += *(const fl4*)(Pv + off);
  }
  u32x2 pkp, pvp;
  pkp[0] = pk2u(ak[0], ak[1]); pkp[1] = pk2u(ak[2], ak[3]);
  pvp[0] = pk2u(av[0], av[1]); pvp[1] = pk2u(av[2], av[3]);
  *(u32x2*)(Xk + base) = pkp;
  *(u32x2*)(Xv + base) = pvp;
}

// ---------------------------------------------------------------------------
// Generic small BT-GEMM: C[i][j] (f16) = sum_e A[i][e] * B[j][e], E=1024.
// ---------------------------------------------------------------------------
__global__ __launch_bounds__(256) void bt64(
    const __fp16* __restrict__ A, long long bsA,
    const __fp16* __restrict__ B, long long bsB,
    __fp16* __restrict__ C, int ldC, long long bsC) {
  constexpr int E = 1024;
  __shared__ __fp16 As[64 * 32];
  __shared__ __fp16 Bs[64 * 32];
  const int t = threadIdx.x;
  const int lane = t & 63, w = t >> 6;
  const int lr = lane & 15, lg = lane >> 4;
  const int i0 = blockIdx.x * 64, j0 = blockIdx.y * 64;
  A += (size_t)blockIdx.z * (size_t)bsA;
  B += (size_t)blockIdx.z * (size_t)bsB;
  C += (size_t)blockIdx.z * (size_t)bsC;
  const int wr = (w >> 1) * 32, wc = (w & 1) * 32;

  f32x4 acc[2][2];
#pragma unroll
  for (int i = 0; i < 2; ++i)
#pragma unroll
    for (int j = 0; j < 2; ++j) acc[i][j] = (f32x4){0.f, 0.f, 0.f, 0.f};

  const int gl_row = w * 16 + (lane >> 2);
  const int gl_ch = (lane & 3) ^ ((lane >> 3) & 3);
  const __fp16* aSrc = A + (size_t)(i0 + gl_row) * E + gl_ch * 8;
  const __fp16* bSrc = B + (size_t)(j0 + gl_row) * E + gl_ch * 8;

  for (int e0 = 0; e0 < E; e0 += 32) {
    __syncthreads();
    gload_lds16(aSrc + e0, (char*)As + w * 1024);
    gload_lds16(bSrc + e0, (char*)Bs + w * 1024);
    __syncthreads();

    f16x8 af[2], bf[2];
#pragma unroll
    for (int i = 0; i < 2; ++i)
      af[i] = rd_swz(As, wr + i * 16 + lr, lg);
#pragma unroll
    for (int j = 0; j < 2; ++j)
      bf[j] = rd_swz(Bs, wc + j * 16 + lr, lg);
#pragma unroll
    for (int i = 0; i < 2; ++i)
#pragma unroll
      for (int j = 0; j < 2; ++j)
        acc[i][j] = MFMA16(af[i], bf[j], acc[i][j]);
  }

#pragma unroll
  for (int i = 0; i < 2; ++i)
#pragma unroll
    for (int j = 0; j < 2; ++j)
#pragma unroll
      for (int r = 0; r < 4; ++r) {
        const int row = i0 + wr + i * 16 + lg * 4 + r;
        const int col = j0 + wc + j * 16 + lr;
        C[(size_t)row * ldC + col] = (__fp16)acc[i][j][r];
      }
}

// ---------------------------------------------------------------------------
// Q-path GEMM v2: Qh[16384][1024] (f16) = X(f32) . WqT^T, 128x128, BK=32.
// Double-buffered pipeline (same schedule as stage1 v5). XCD swizzle: the
// 8 n-blocks of one m-tile at flat ids {g*64 + n*8 + p} -> same XCD.
// ---------------------------------------------------------------------------
__global__ __launch_bounds__(256) void gemm_q(
    const float* __restrict__ X,
    const __fp16* __restrict__ WT,   // [1024][1024], WT[n][k] = W[k][n]
    __fp16* __restrict__ Q) {
  constexpr int K = 1024, N = 1024;
  __shared__ __fp16 Xs[2][128 * 32];
  __shared__ __fp16 Ws[2][128 * 32];
  const int t = threadIdx.x;
  const int lane = t & 63, w = t >> 6;
  const int lr = lane & 15, lg = lane >> 4;
  // XCD decode: fid = g*64 + n0i*8 + p ; m-tile = g*8+p
  const int fid = blockIdx.x;
  const int g = fid >> 6, s = fid & 63;
  const int n0 = (s >> 3) * 128;
  const int m0 = (g * 8 + (s & 7)) * 128;
  const int wr = (w >> 1) * 64, wc = (w & 1) * 64;

  f32x4 acc[4][4];
#pragma unroll
  for (int i = 0; i < 4; ++i)
#pragma unroll
    for (int j = 0; j < 4; ++j) acc[i][j] = (f32x4){0.f, 0.f, 0.f, 0.f};

  const int xrow = t >> 2;
  const int xpos = (t & 3) ^ ((t >> 3) & 3);
  const float* xSrc1 = X + (size_t)(m0 + xrow) * K + (t & 3) * 8;
  const float* xSrc2 = xSrc1 + (size_t)64 * K;
  const int gl_row = w * 16 + (lane >> 2);
  const int gl_ch = (lane & 3) ^ ((lane >> 3) & 3);
  const __fp16* wSrc0 = WT + (size_t)(n0 + gl_row) * K + gl_ch * 8;
  const __fp16* wSrc1 = WT + (size_t)(n0 + 64 + gl_row) * K + gl_ch * 8;

  // ---- prologue: stage k0=0 into buffer 0
  gload_lds16(wSrc0, (char*)Ws[0] + w * 1024);
  gload_lds16(wSrc1, (char*)Ws[0] + 4096 + w * 1024);
  fl4 a0 = *(const fl4*)(xSrc1);
  fl4 a1 = *(const fl4*)(xSrc1 + 4);
  fl4 a2 = *(const fl4*)(xSrc2);
  fl4 a3 = *(const fl4*)(xSrc2 + 4);
  __syncthreads();
  *(f16x8*)((char*)Xs[0] + xrow * 64 + xpos * 16) = pk8(a0, a1);
  *(f16x8*)((char*)Xs[0] + (64 + xrow) * 64 + xpos * 16) = pk8(a2, a3);
  __syncthreads();

  for (int it = 0; it < 32; ++it) {
    const int cur = it & 1, nxt = cur ^ 1;
    if (it < 31) {
      const int k1 = (it + 1) * 32;
      gload_lds16(wSrc0 + k1, (char*)Ws[nxt] + w * 1024);
      gload_lds16(wSrc1 + k1, (char*)Ws[nxt] + 4096 + w * 1024);
      a0 = *(const fl4*)(xSrc1 + k1);
      a1 = *(const fl4*)(xSrc1 + k1 + 4);
      a2 = *(const fl4*)(xSrc2 + k1);
      a3 = *(const fl4*)(xSrc2 + k1 + 4);
    }
    f16x8 af[4], bf[4];
#pragma unroll
    for (int i = 0; i < 4; ++i)
      af[i] = rd_swz(Xs[cur], wr + i * 16 + lr, lg);
#pragma unroll
    for (int j = 0; j < 4; ++j)
      bf[j] = rd_swz(Ws[cur], wc + j * 16 + lr, lg);
#pragma unroll
    for (int i = 0; i < 4; ++i)
#pragma unroll
      for (int j = 0; j < 4; ++j)
        acc[i][j] = MFMA16(af[i], bf[j], acc[i][j]);
    __syncthreads();  // prefetch landed during compute; cur readers done
    if (it < 31) {
      *(f16x8*)((char*)Xs[nxt] + xrow * 64 + xpos * 16) = pk8(a0, a1);
      *(f16x8*)((char*)Xs[nxt] + (64 + xrow) * 64 + xpos * 16) = pk8(a2, a3);
    }
    __syncthreads();  // Xs[nxt] visible
  }

#pragma unroll
  for (int i = 0; i < 4; ++i)
#pragma unroll
    for (int j = 0; j < 4; ++j)
#pragma unroll
      for (int r = 0; r < 4; ++r) {
        const int row = m0 + wr + i * 16 + lg * 4 + r;
        const int col = n0 + wc + j * 16 + lr;
        Q[(size_t)row * N + col] = (__fp16)acc[i][j][r];
      }
}

// ---------------------------------------------------------------------------
// Attention v3: block = 4 waves, 128 Q-rows of one (b,h); grid 2048.
// 32KB LDS (K then V), swapped QK^T, in-register P via cvt_pk + ds_bpermute.
// ---------------------------------------------------------------------------
__global__ __launch_bounds__(256) void attn_k(
    const __fp16* __restrict__ Q,    // [b*4096][1024]
    const __fp16* __restrict__ Kp,   // [b][256][1024]
    const __fp16* __restrict__ Vpt,  // [b][1024][256]
    float* __restrict__ O) {         // [b*4096][1024] f32
  __shared__ __fp16 KV[256 * 64];    // 32KB: K tile, then V^T tile
  const int t = threadIdx.x;
  const int lane = t & 63, w = t >> 6;
  const int lr = lane & 15, lg = lane >> 4;
  const int bh = blockIdx.x >> 5, rb = blockIdx.x & 31;
  const int b = bh >> 4, h = bh & 15;
  const int m0 = rb * 128 + w * 32;

  const __fp16* Kph = Kp + (size_t)b * 256 * 1024 + h * 64;
  const __fp16* Vph = Vpt + ((size_t)b * 1024 + h * 64) * 256;
  const __fp16* Qh = Q + ((size_t)(b * 4096 + m0)) * 1024 + h * 64;

#pragma unroll
  for (int i = 0; i < 8; ++i) {
    const int kr = (i * 4 + w) * 8 + (lane >> 3);
    gload_lds16(Kph + (size_t)kr * 1024 + (((lane & 7) ^ (kr & 7)) * 8),
                (char*)KV + (i * 4 + w) * 1024);
  }

  f16x8 aq[2][2];
#pragma unroll
  for (int mi = 0; mi < 2; ++mi)
#pragma unroll
    for (int s = 0; s < 2; ++s)
      aq[mi][s] =
          *(const f16x8*)(Qh + (size_t)(mi * 16 + lr) * 1024 + s * 32 + lg * 8);

  __syncthreads();  // K staged

  f32x4 dots[2][16];
#pragma unroll
  for (int mi = 0; mi < 2; ++mi)
#pragma unroll
    for (int jt = 0; jt < 16; ++jt) dots[mi][jt] = (f32x4){0.f, 0.f, 0.f, 0.f};
#pragma unroll
  for (int jt = 0; jt < 16; ++jt) {
    const int r = jt * 16 + lr;
    f16x8 k0 = *(const f16x8*)((const char*)KV + r * 128 + ((lg ^ (r & 7)) * 16));
    f16x8 k1 =
        *(const f16x8*)((const char*)KV + r * 128 + (((4 + lg) ^ (r & 7)) * 16));
    dots[0][jt] = MFMA16(k0, aq[0][0], dots[0][jt]);
    dots[0][jt] = MFMA16(k1, aq[0][1], dots[0][jt]);
    dots[1][jt] = MFMA16(k0, aq[1][0], dots[1][jt]);
    dots[1][jt] = MFMA16(k1, aq[1][1], dots[1][jt]);
  }

  unsigned cpk[2][16][2];
  float smv[2];
#pragma unroll
  for (int mi = 0; mi < 2; ++mi) {
    float mx = -1e30f;
#pragma unroll
    for (int jt = 0; jt < 16; ++jt)
#pragma unroll
      for (int r = 0; r < 4; ++r) mx = fmaxf(mx, dots[mi][jt][r]);
    mx = fmaxf(mx, __shfl_xor(mx, 16, 64));
    mx = fmaxf(mx, __shfl_xor(mx, 32, 64));
    float sm = 0.f;
#pragma unroll
    for (int jt = 0; jt < 16; ++jt) {
#pragma unroll
      for (int r = 0; r < 4; ++r) {
        float p = __expf(dots[mi][jt][r] - mx);
        dots[mi][jt][r] = p;
        sm += p;
      }
      cpk[mi][jt][0] = pk2u(dots[mi][jt][0], dots[mi][jt][1]);
      cpk[mi][jt][1] = pk2u(dots[mi][jt][2], dots[mi][jt][3]);
    }
    sm += __shfl_xor(sm, 16, 64);
    sm += __shfl_xor(sm, 32, 64);
    smv[mi] = sm;
  }

  __syncthreads();  // all waves done reading K

#pragma unroll
  for (int i = 0; i < 8; ++i) {
    const int dd = (i * 4 + w) * 2 + (lane >> 5);
    gload_lds16(Vph + (size_t)dd * 256 + (((lane & 31) ^ (dd & 7)) * 8),
                (char*)KV + (i * 4 + w) * 1024);
  }
  __syncthreads();  // V staged

#pragma unroll
  for (int mi = 0; mi < 2; ++mi) {
    f32x4 o[4];
#pragma unroll
    for (int j = 0; j < 4; ++j) o[j] = (f32x4){0.f, 0.f, 0.f, 0.f};
#pragma unroll
    for (int ks = 0; ks < 8; ++ks) {
      u32x4 wds;
#pragma unroll
      for (int m = 0; m < 4; ++m) {
        const int addr = ((((lane & 16) >> 3) + (m >> 1)) * 16 + lr) * 4;
        const int a0 = __builtin_amdgcn_ds_bpermute(
            addr, (int)cpk[mi][ks * 2][m & 1]);
        const int a1 = __builtin_amdgcn_ds_bpermute(
            addr, (int)cpk[mi][ks * 2 + 1][m & 1]);
        wds[m] = (unsigned)((lg >> 1) ? a1 : a0);
      }
      f16x8 pa = __builtin_bit_cast(f16x8, wds);
#pragma unroll
      for (int jt2 = 0; jt2 < 4; ++jt2) {
        const int dd = jt2 * 16 + lr;
        f16x8 bv = *(const f16x8*)((const char*)KV + dd * 512 +
                                   (((ks * 4 + lg) ^ (dd & 7)) * 16));
        o[jt2] = MFMA16(pa, bv, o[jt2]);
      }
    }

    float rs[4];
#pragma unroll
    for (int r = 0; r < 4; ++r)
      rs[r] = 1.f / __shfl(smv[mi], (lane & 48) + lg * 4 + r, 64);
#pragma unroll
    for (int jt2 = 0; jt2 < 4; ++jt2)
#pragma unroll
      for (int r = 0; r < 4; ++r) {
        const size_t row = (size_t)(b * 4096 + m0 + mi * 16 + lg * 4 + r);
        O[row * 1024 + h * 64 + jt2 * 16 + lr] = o[jt2][r] * rs[r];
      }
  }
}

// ---------------------------------------------------------------------------
extern "C" void kernel_launch(void* const* d_in, const int* in_sizes, int n_in,
                              void* d_out, int out_size, void* d_ws, size_t ws_size,
                              hipStream_t stream) {
  (void)in_sizes; (void)n_in; (void)out_size; (void)ws_size;
  const float* x  = (const float*)d_in[0];
  const float* Wq = (const float*)d_in[1];
  const float* Wk = (const float*)d_in[2];
  const float* Wv = (const float*)d_in[3];
  const float* pk = (const float*)d_in[4];
  const float* pv = (const float*)d_in[5];
  float* out = (float*)d_out;

  // ws layout (f16 halfwords), total ~52.4 MB.
  // The Qh region (33.5 MB) doubles as the f32 partials buffer (32 MB) for
  // stage1; gemm_q overwrites it later (stream-ordered after stage1_reduce).
  __fp16* Qh  = (__fp16*)d_ws;                       // 16384*1024 f16
  __fp16* WqT = Qh  + (size_t)16384 * 1024;          // 1024*1024 each
  __fp16* WkT = WqT + (size_t)1024 * 1024;
  __fp16* WvT = WkT + (size_t)1024 * 1024;
  __fp16* pkT = WvT + (size_t)1024 * 1024;           // 256*4096 each
  __fp16* pvT = pkT + (size_t)256 * 4096;
  __fp16* Xk  = pvT + (size_t)256 * 4096;            // 4*256*1024 each
  __fp16* Xv  = Xk  + (size_t)4 * 256 * 1024;
  __fp16* Kp  = Xv  + (size_t)4 * 256 * 1024;
  __fp16* Vpt = Kp  + (size_t)4 * 256 * 1024;
  float* Pk = (float*)d_ws;                          // 16*256*1024 f32 each
  float* Pv = Pk + (size_t)16 * 256 * 1024;

  const dim3 bb(256);

  // 0. one-time transposes (f32 -> f16)
  tr_cvt<<<dim3(32, 32), bb, 0, stream>>>(Wq, WqT, 1024, 1024);
  tr_cvt<<<dim3(32, 32), bb, 0, stream>>>(Wk, WkT, 1024, 1024);
  tr_cvt<<<dim3(32, 32), bb, 0, stream>>>(Wv, WvT, 1024, 1024);
  tr_cvt<<<dim3(8, 128), bb, 0, stream>>>(pk, pkT, 4096, 256);
  tr_cvt<<<dim3(8, 128), bb, 0, stream>>>(pv, pvT, 4096, 256);

  // 1. split-K low-rank projections of X + reduce (pipelined, XCD-swizzled)
  stage1_partial<<<dim3(1024), bb, 0, stream>>>(pkT, pvT, x, Pk, Pv);
  stage1_reduce<<<dim3(1024), bb, 0, stream>>>(Pk, Pv, Xk, Xv);

  // 2. Kp = Xk . Wk ; VpT = (Xv . Wv)^T
  bt64<<<dim3(4, 16, 4), bb, 0, stream>>>(Xk, 256LL * 1024, WkT, 0LL,
                                          Kp, 1024, 256LL * 1024);
  bt64<<<dim3(16, 4, 4), bb, 0, stream>>>(WvT, 0LL, Xv, 256LL * 1024,
                                          Vpt, 256, 1024LL * 256);

  // 3. Q projection (pipelined, XCD-swizzled; overwrites partials region)
  gemm_q<<<dim3(1024), bb, 0, stream>>>(x, WqT, Qh);

  // 4. attention (32KB LDS, swapped QK, in-register P)
  attn_k<<<dim3(2048), bb, 0, stream>>>(Qh, Kp, Vpt, out);
}

// Round 12
// 189.222 us; speedup vs baseline: 1.1418x; 1.0415x over previous
//
#include <hip/hip_runtime.h>

// ---------------------------------------------------------------------------
// Linformer self-attention, fp32 I/O, fp16 MFMA internally, MI355X (gfx950)
// b=4 n=4096 d=1024 h=16 dh=64 k=256  (no 1/sqrt(dh) scale per reference)
//
// Key algebra: proj_k^T (X Wk) == (proj_k^T X) Wk  -> K/V paths cost 4x less.
// This round: xprep converts X -> f16 row-major + transposed ONCE (stored in
// d_out, dead until attn overwrites); stage1/gemm_q become pure global_load_lds
// GEMMs (BK=64, 128B-row source swizzle) with zero VALU staging.
// ---------------------------------------------------------------------------

typedef __fp16 f16x8 __attribute__((ext_vector_type(8)));
typedef __fp16 f16x2 __attribute__((ext_vector_type(2)));
typedef float fl4 __attribute__((ext_vector_type(4)));
typedef float f32x4 __attribute__((ext_vector_type(4)));
typedef unsigned int u32x2 __attribute__((ext_vector_type(2)));
typedef unsigned int u32x4 __attribute__((ext_vector_type(4)));

#define MFMA16(a, b, c) __builtin_amdgcn_mfma_f32_16x16x32_f16((a), (b), (c), 0, 0, 0)

__device__ __forceinline__ unsigned int pk2u(float a, float b) {
  f16x2 p = __builtin_amdgcn_cvt_pkrtz(a, b);  // low = a, high = b
  return __builtin_bit_cast(unsigned int, p);
}

__device__ __forceinline__ f16x8 pk8(fl4 a, fl4 b) {
  f16x2 p0 = __builtin_amdgcn_cvt_pkrtz(a[0], a[1]);
  f16x2 p1 = __builtin_amdgcn_cvt_pkrtz(a[2], a[3]);
  f16x2 p2 = __builtin_amdgcn_cvt_pkrtz(b[0], b[1]);
  f16x2 p3 = __builtin_amdgcn_cvt_pkrtz(b[2], b[3]);
  f16x8 r;
  r[0] = p0[0]; r[1] = p0[1]; r[2] = p1[0]; r[3] = p1[1];
  r[4] = p2[0]; r[5] = p2[1]; r[6] = p3[0]; r[7] = p3[1];
  return r;
}

__device__ __forceinline__ void gload_lds16(const __fp16* g, void* lds_base) {
  __builtin_amdgcn_global_load_lds(
      (const __attribute__((address_space(1))) void*)g,
      (__attribute__((address_space(3))) void*)lds_base, 16, 0, 0);
}

// 64B-row tile fragment read (legacy swizzle, used by bt64)
__device__ __forceinline__ f16x8 rd_swz(const __fp16* base, int row, int lg) {
  return *(const f16x8*)((const char*)base + row * 64 +
                         ((lg ^ ((row >> 1) & 3)) * 16));
}

// 128B-row tile fragment read: logical 16B chunk `ch` of `row`
__device__ __forceinline__ f16x8 rd128(const __fp16* base, int row, int ch) {
  return *(const f16x8*)((const char*)base + row * 128 +
                         ((ch ^ (row & 7)) * 16));
}

// ---------------------------------------------------------------------------
// Transpose + convert: in f32 [R][C] -> out f16 [C][R]. 32x32 tiles.
// ---------------------------------------------------------------------------
__global__ __launch_bounds__(256) void tr_cvt(
    const float* __restrict__ in, __fp16* __restrict__ out, int R, int C) {
  __shared__ float tile[32][33];
  const int t = threadIdx.x;
  const int c0 = blockIdx.x * 32, r0 = blockIdx.y * 32;
  {
    const int r = t >> 3, cg = (t & 7) * 4;
    fl4 v = *(const fl4*)(in + (size_t)(r0 + r) * C + c0 + cg);
    tile[r][cg] = v[0]; tile[r][cg + 1] = v[1];
    tile[r][cg + 2] = v[2]; tile[r][cg + 3] = v[3];
  }
  __syncthreads();
  {
    const int cc = t >> 3, rg = (t & 7) * 4;
    u32x2 p;
    p[0] = pk2u(tile[rg + 0][cc], tile[rg + 1][cc]);
    p[1] = pk2u(tile[rg + 2][cc], tile[rg + 3][cc]);
    *(u32x2*)(out + (size_t)(c0 + cc) * R + r0 + rg) = p;
  }
}

// ---------------------------------------------------------------------------
// xprep: X f32 [b][4096][1024] -> Xf16 [b][4096][1024] + XT f16 [b][1024][4096]
// Tile 32 n x 64 d per block; both outputs written once. ~134MB traffic.
// ---------------------------------------------------------------------------
__global__ __launch_bounds__(256) void xprep(
    const float* __restrict__ X, __fp16* __restrict__ Xf,
    __fp16* __restrict__ XT) {
  __shared__ float tile[32][65];
  const int t = threadIdx.x;
  const int n0 = blockIdx.x * 32, d0 = blockIdx.y * 64, b = blockIdx.z;
  const float* src = X + ((size_t)b * 4096 + n0) * 1024 + d0;
  {
    const int r = t >> 3, cg = (t & 7) * 8;
    fl4 v0 = *(const fl4*)(src + (size_t)r * 1024 + cg);
    fl4 v1 = *(const fl4*)(src + (size_t)r * 1024 + cg + 4);
    *(f16x8*)(Xf + ((size_t)b * 4096 + n0 + r) * 1024 + d0 + cg) = pk8(v0, v1);
#pragma unroll
    for (int j = 0; j < 4; ++j) {
      tile[r][cg + j] = v0[j];
      tile[r][cg + 4 + j] = v1[j];
    }
  }
  __syncthreads();
  {
    const int d = t >> 2, ng = (t & 3) * 8;
    fl4 a, c;
#pragma unroll
    for (int j = 0; j < 4; ++j) {
      a[j] = tile[ng + j][d];
      c[j] = tile[ng + 4 + j][d];
    }
    *(f16x8*)(XT + ((size_t)b * 1024 + d0 + d) * 4096 + n0 + ng) = pk8(a, c);
  }
}

// ---------------------------------------------------------------------------
// Stage 1 v7: Pk[z][kk][dd] = sum_{n in 1024-chunk c} pkT[kk][n]*XT[b][dd][n]
// (z = c*4+b). Tile 64kk x 64dd, BK=64, 16 iters, pure gload_lds (3 tiles of
// 64x64 f16, 128B rows, source chunk pre-swizzled c8^r8). XCD-swizzled grid:
// fid = g*32 + kk*8 + p ; (dd,z) = g*8+p -> 4 kk-blocks share X^T rows in L2.
// ---------------------------------------------------------------------------
__global__ __launch_bounds__(256) void stage1_partial(
    const __fp16* __restrict__ pkT,  // [256][4096]
    const __fp16* __restrict__ pvT,  // [256][4096]
    const __fp16* __restrict__ XT,   // [b][1024][4096]
    float* __restrict__ Pk,          // [16][256][1024] f32 partials
    float* __restrict__ Pv) {        // [16][256][1024]
  __shared__ __fp16 Ak[64 * 64];  // 8KB each, 128B rows
  __shared__ __fp16 Av[64 * 64];
  __shared__ __fp16 Bx[64 * 64];
  const int t = threadIdx.x;
  const int lane = t & 63, w = t >> 6;
  const int lr = lane & 15, lg = lane >> 4;
  const int fid = blockIdx.x;
  const int g = fid >> 5, s5 = fid & 31;
  const int kk0 = (s5 >> 3) * 64, p8 = s5 & 7;
  const int pr = g * 8 + p8;
  const int dd0 = (pr & 15) * 64;
  const int z = pr >> 4, b = z & 3, c = z >> 2;
  const int wr = (w >> 1) * 32, wc = (w & 1) * 32;

  f32x4 acck[2][2], accv[2][2];
#pragma unroll
  for (int i = 0; i < 2; ++i)
#pragma unroll
    for (int j = 0; j < 2; ++j) {
      acck[i][j] = (f32x4){0.f, 0.f, 0.f, 0.f};
      accv[i][j] = (f32x4){0.f, 0.f, 0.f, 0.f};
    }

  // gload: inst i covers rows i*32 + w*8 + r8 ; row&7 == r8 for all
  const int r8 = lane >> 3, c8 = lane & 7;
  const int ssw = ((c8 ^ r8) * 8);
  const __fp16* pkS0 = pkT + (size_t)(kk0 + w * 8 + r8) * 4096 + c * 1024 + ssw;
  const __fp16* pkS1 = pkS0 + (size_t)32 * 4096;
  const __fp16* pvS0 = pvT + (size_t)(kk0 + w * 8 + r8) * 4096 + c * 1024 + ssw;
  const __fp16* pvS1 = pvS0 + (size_t)32 * 4096;
  const __fp16* xS0 =
      XT + ((size_t)b * 1024 + dd0 + w * 8 + r8) * 4096 + c * 1024 + ssw;
  const __fp16* xS1 = xS0 + (size_t)32 * 4096;

  for (int it = 0; it < 16; ++it) {
    const int n0 = it * 64;
    __syncthreads();
    gload_lds16(pkS0 + n0, (char*)Ak + w * 1024);
    gload_lds16(pkS1 + n0, (char*)Ak + 4096 + w * 1024);
    gload_lds16(pvS0 + n0, (char*)Av + w * 1024);
    gload_lds16(pvS1 + n0, (char*)Av + 4096 + w * 1024);
    gload_lds16(xS0 + n0, (char*)Bx + w * 1024);
    gload_lds16(xS1 + n0, (char*)Bx + 4096 + w * 1024);
    __syncthreads();

#pragma unroll
    for (int s = 0; s < 2; ++s) {
      f16x8 ak[2], av[2], bx[2];
#pragma unroll
      for (int i = 0; i < 2; ++i) {
        ak[i] = rd128(Ak, wr + i * 16 + lr, s * 4 + lg);
        av[i] = rd128(Av, wr + i * 16 + lr, s * 4 + lg);
      }
#pragma unroll
      for (int j = 0; j < 2; ++j)
        bx[j] = rd128(Bx, wc + j * 16 + lr, s * 4 + lg);
#pragma unroll
      for (int i = 0; i < 2; ++i)
#pragma unroll
        for (int j = 0; j < 2; ++j) {
          acck[i][j] = MFMA16(ak[i], bx[j], acck[i][j]);
          accv[i][j] = MFMA16(av[i], bx[j], accv[i][j]);
        }
    }
  }

#pragma unroll
  for (int i = 0; i < 2; ++i)
#pragma unroll
    for (int j = 0; j < 2; ++j)
#pragma unroll
      for (int r = 0; r < 4; ++r) {
        const size_t row = (size_t)z * 256 + kk0 + wr + i * 16 + lg * 4 + r;
        const int col = dd0 + wc + j * 16 + lr;
        Pk[row * 1024 + col] = acck[i][j][r];
        Pv[row * 1024 + col] = accv[i][j][r];
      }
}

// ---------------------------------------------------------------------------
// Stage 1 reduce: Xk = f16(sum_c Pk[c*4+b]), Xv likewise. 4 f32/thread.
// ---------------------------------------------------------------------------
__global__ __launch_bounds__(256) void stage1_reduce(
    const float* __restrict__ Pk, const float* __restrict__ Pv,
    __fp16* __restrict__ Xk, __fp16* __restrict__ Xv) {
  const size_t base = ((size_t)blockIdx.x * 256 + threadIdx.x) * 4;
  const int b = (int)(base >> 18);          // 256K elems per batch slab
  const size_t rem = base & 0x3FFFFu;
  fl4 ak = (fl4){0.f, 0.f, 0.f, 0.f}, av = (fl4){0.f, 0.f, 0.f, 0.f};
#pragma unroll
  for (int c = 0; c < 4; ++c) {
    const size_t off = (((size_t)(c * 4 + b)) << 18) + rem;
    ak += *(const fl4*)(Pk + off);
    av += *(const fl4*)(Pv + off);
  }
  u32x2 pkp, pvp;
  pkp[0] = pk2u(ak[0], ak[1]); pkp[1] = pk2u(ak[2], ak[3]);
  pvp[0] = pk2u(av[0], av[1]); pvp[1] = pk2u(av[2], av[3]);
  *(u32x2*)(Xk + base) = pkp;
  *(u32x2*)(Xv + base) = pvp;
}

// ---------------------------------------------------------------------------
// Generic small BT-GEMM: C[i][j] (f16) = sum_e A[i][e] * B[j][e], E=1024.
// ---------------------------------------------------------------------------
__global__ __launch_bounds__(256) void bt64(
    const __fp16* __restrict__ A, long long bsA,
    const __fp16* __restrict__ B, long long bsB,
    __fp16* __restrict__ C, int ldC, long long bsC) {
  constexpr int E = 1024;
  __shared__ __fp16 As[64 * 32];
  __shared__ __fp16 Bs[64 * 32];
  const int t = threadIdx.x;
  const int lane = t & 63, w = t >> 6;
  const int lr = lane & 15, lg = lane >> 4;
  const int i0 = blockIdx.x * 64, j0 = blockIdx.y * 64;
  A += (size_t)blockIdx.z * (size_t)bsA;
  B += (size_t)blockIdx.z * (size_t)bsB;
  C += (size_t)blockIdx.z * (size_t)bsC;
  const int wr = (w >> 1) * 32, wc = (w & 1) * 32;

  f32x4 acc[2][2];
#pragma unroll
  for (int i = 0; i < 2; ++i)
#pragma unroll
    for (int j = 0; j < 2; ++j) acc[i][j] = (f32x4){0.f, 0.f, 0.f, 0.f};

  const int gl_row = w * 16 + (lane >> 2);
  const int gl_ch = (lane & 3) ^ ((lane >> 3) & 3);
  const __fp16* aSrc = A + (size_t)(i0 + gl_row) * E + gl_ch * 8;
  const __fp16* bSrc = B + (size_t)(j0 + gl_row) * E + gl_ch * 8;

  for (int e0 = 0; e0 < E; e0 += 32) {
    __syncthreads();
    gload_lds16(aSrc + e0, (char*)As + w * 1024);
    gload_lds16(bSrc + e0, (char*)Bs + w * 1024);
    __syncthreads();

    f16x8 af[2], bf[2];
#pragma unroll
    for (int i = 0; i < 2; ++i)
      af[i] = rd_swz(As, wr + i * 16 + lr, lg);
#pragma unroll
    for (int j = 0; j < 2; ++j)
      bf[j] = rd_swz(Bs, wc + j * 16 + lr, lg);
#pragma unroll
    for (int i = 0; i < 2; ++i)
#pragma unroll
      for (int j = 0; j < 2; ++j)
        acc[i][j] = MFMA16(af[i], bf[j], acc[i][j]);
  }

#pragma unroll
  for (int i = 0; i < 2; ++i)
#pragma unroll
    for (int j = 0; j < 2; ++j)
#pragma unroll
      for (int r = 0; r < 4; ++r) {
        const int row = i0 + wr + i * 16 + lg * 4 + r;
        const int col = j0 + wc + j * 16 + lr;
        C[(size_t)row * ldC + col] = (__fp16)acc[i][j][r];
      }
}

// ---------------------------------------------------------------------------
// Q-path GEMM v4: Qh[16384][1024] = Xf16 . WqT^T, 128x128, BK=64, 16 iters.
// Pure gload_lds both operands (16KB each, 128B rows, src chunk c8^r8).
// XCD swizzle: fid = g*64 + n*8 + p -> m-tile g*8+p; 8 n-blocks share X rows.
// ---------------------------------------------------------------------------
__global__ __launch_bounds__(256) void gemm_q(
    const __fp16* __restrict__ Xf,   // [16384][1024] f16
    const __fp16* __restrict__ WT,   // [1024][1024], WT[n][k] = W[k][n]
    __fp16* __restrict__ Q) {
  constexpr int K = 1024, N = 1024;
  __shared__ __fp16 Xs[128 * 64];  // 16KB
  __shared__ __fp16 Ws[128 * 64];
  const int t = threadIdx.x;
  const int lane = t & 63, w = t >> 6;
  const int lr = lane & 15, lg = lane >> 4;
  const int fid = blockIdx.x;
  const int g = fid >> 6, s6 = fid & 63;
  const int n0 = (s6 >> 3) * 128;
  const int m0 = (g * 8 + (s6 & 7)) * 128;
  const int wr = (w >> 1) * 64, wc = (w & 1) * 64;

  f32x4 acc[4][4];
#pragma unroll
  for (int i = 0; i < 4; ++i)
#pragma unroll
    for (int j = 0; j < 4; ++j) acc[i][j] = (f32x4){0.f, 0.f, 0.f, 0.f};

  const int r8 = lane >> 3, c8 = lane & 7;
  const int ssw = ((c8 ^ r8) * 8);
  const __fp16* xS = Xf + (size_t)(m0 + w * 8 + r8) * K + ssw;
  const __fp16* wS = WT + (size_t)(n0 + w * 8 + r8) * K + ssw;

  for (int it = 0; it < 16; ++it) {
    const int k0 = it * 64;
    __syncthreads();
#pragma unroll
    for (int i = 0; i < 4; ++i) {
      gload_lds16(xS + (size_t)i * 32 * K + k0, (char*)Xs + i * 4096 + w * 1024);
      gload_lds16(wS + (size_t)i * 32 * K + k0, (char*)Ws + i * 4096 + w * 1024);
    }
    __syncthreads();

#pragma unroll
    for (int s = 0; s < 2; ++s) {
      f16x8 af[4], bf[4];
#pragma unroll
      for (int i = 0; i < 4; ++i)
        af[i] = rd128(Xs, wr + i * 16 + lr, s * 4 + lg);
#pragma unroll
      for (int j = 0; j < 4; ++j)
        bf[j] = rd128(Ws, wc + j * 16 + lr, s * 4 + lg);
#pragma unroll
      for (int i = 0; i < 4; ++i)
#pragma unroll
        for (int j = 0; j < 4; ++j)
          acc[i][j] = MFMA16(af[i], bf[j], acc[i][j]);
    }
  }

#pragma unroll
  for (int i = 0; i < 4; ++i)
#pragma unroll
    for (int j = 0; j < 4; ++j)
#pragma unroll
      for (int r = 0; r < 4; ++r) {
        const int row = m0 + wr + i * 16 + lg * 4 + r;
        const int col = n0 + wc + j * 16 + lr;
        Q[(size_t)row * N + col] = (__fp16)acc[i][j][r];
      }
}

// ---------------------------------------------------------------------------
// Attention v3: block = 4 waves, 128 Q-rows of one (b,h); grid 2048.
// 32KB LDS (K then V), swapped QK^T, in-register P via cvt_pk + ds_bpermute.
// ---------------------------------------------------------------------------
__global__ __launch_bounds__(256) void attn_k(
    const __fp16* __restrict__ Q,    // [b*4096][1024]
    const __fp16* __restrict__ Kp,   // [b][256][1024]
    const __fp16* __restrict__ Vpt,  // [b][1024][256]
    float* __restrict__ O) {         // [b*4096][1024] f32
  __shared__ __fp16 KV[256 * 64];    // 32KB: K tile, then V^T tile
  const int t = threadIdx.x;
  const int lane = t & 63, w = t >> 6;
  const int lr = lane & 15, lg = lane >> 4;
  const int bh = blockIdx.x >> 5, rb = blockIdx.x & 31;
  const int b = bh >> 4, h = bh & 15;
  const int m0 = rb * 128 + w * 32;

  const __fp16* Kph = Kp + (size_t)b * 256 * 1024 + h * 64;
  const __fp16* Vph = Vpt + ((size_t)b * 1024 + h * 64) * 256;
  const __fp16* Qh = Q + ((size_t)(b * 4096 + m0)) * 1024 + h * 64;

#pragma unroll
  for (int i = 0; i < 8; ++i) {
    const int kr = (i * 4 + w) * 8 + (lane >> 3);
    gload_lds16(Kph + (size_t)kr * 1024 + (((lane & 7) ^ (kr & 7)) * 8),
                (char*)KV + (i * 4 + w) * 1024);
  }

  f16x8 aq[2][2];
#pragma unroll
  for (int mi = 0; mi < 2; ++mi)
#pragma unroll
    for (int s = 0; s < 2; ++s)
      aq[mi][s] =
          *(const f16x8*)(Qh + (size_t)(mi * 16 + lr) * 1024 + s * 32 + lg * 8);

  __syncthreads();  // K staged

  f32x4 dots[2][16];
#pragma unroll
  for (int mi = 0; mi < 2; ++mi)
#pragma unroll
    for (int jt = 0; jt < 16; ++jt) dots[mi][jt] = (f32x4){0.f, 0.f, 0.f, 0.f};
#pragma unroll
  for (int jt = 0; jt < 16; ++jt) {
    const int r = jt * 16 + lr;
    f16x8 k0 = *(const f16x8*)((const char*)KV + r * 128 + ((lg ^ (r & 7)) * 16));
    f16x8 k1 =
        *(const f16x8*)((const char*)KV + r * 128 + (((4 + lg) ^ (r & 7)) * 16));
    dots[0][jt] = MFMA16(k0, aq[0][0], dots[0][jt]);
    dots[0][jt] = MFMA16(k1, aq[0][1], dots[0][jt]);
    dots[1][jt] = MFMA16(k0, aq[1][0], dots[1][jt]);
    dots[1][jt] = MFMA16(k1, aq[1][1], dots[1][jt]);
  }

  unsigned cpk[2][16][2];
  float smv[2];
#pragma unroll
  for (int mi = 0; mi < 2; ++mi) {
    float mx = -1e30f;
#pragma unroll
    for (int jt = 0; jt < 16; ++jt)
#pragma unroll
      for (int r = 0; r < 4; ++r) mx = fmaxf(mx, dots[mi][jt][r]);
    mx = fmaxf(mx, __shfl_xor(mx, 16, 64));
    mx = fmaxf(mx, __shfl_xor(mx, 32, 64));
    float sm = 0.f;
#pragma unroll
    for (int jt = 0; jt < 16; ++jt) {
#pragma unroll
      for (int r = 0; r < 4; ++r) {
        float p = __expf(dots[mi][jt][r] - mx);
        dots[mi][jt][r] = p;
        sm += p;
      }
      cpk[mi][jt][0] = pk2u(dots[mi][jt][0], dots[mi][jt][1]);
      cpk[mi][jt][1] = pk2u(dots[mi][jt][2], dots[mi][jt][3]);
    }
    sm += __shfl_xor(sm, 16, 64);
    sm += __shfl_xor(sm, 32, 64);
    smv[mi] = sm;
  }

  __syncthreads();  // all waves done reading K

#pragma unroll
  for (int i = 0; i < 8; ++i) {
    const int dd = (i * 4 + w) * 2 + (lane >> 5);
    gload_lds16(Vph + (size_t)dd * 256 + (((lane & 31) ^ (dd & 7)) * 8),
                (char*)KV + (i * 4 + w) * 1024);
  }
  __syncthreads();  // V staged

#pragma unroll
  for (int mi = 0; mi < 2; ++mi) {
    f32x4 o[4];
#pragma unroll
    for (int j = 0; j < 4; ++j) o[j] = (f32x4){0.f, 0.f, 0.f, 0.f};
#pragma unroll
    for (int ks = 0; ks < 8; ++ks) {
      u32x4 wds;
#pragma unroll
      for (int m = 0; m < 4; ++m) {
        const int addr = ((((lane & 16) >> 3) + (m >> 1)) * 16 + lr) * 4;
        const int a0 = __builtin_amdgcn_ds_bpermute(
            addr, (int)cpk[mi][ks * 2][m & 1]);
        const int a1 = __builtin_amdgcn_ds_bpermute(
            addr, (int)cpk[mi][ks * 2 + 1][m & 1]);
        wds[m] = (unsigned)((lg >> 1) ? a1 : a0);
      }
      f16x8 pa = __builtin_bit_cast(f16x8, wds);
#pragma unroll
      for (int jt2 = 0; jt2 < 4; ++jt2) {
        const int dd = jt2 * 16 + lr;
        f16x8 bv = *(const f16x8*)((const char*)KV + dd * 512 +
                                   (((ks * 4 + lg) ^ (dd & 7)) * 16));
        o[jt2] = MFMA16(pa, bv, o[jt2]);
      }
    }

    float rs[4];
#pragma unroll
    for (int r = 0; r < 4; ++r)
      rs[r] = 1.f / __shfl(smv[mi], (lane & 48) + lg * 4 + r, 64);
#pragma unroll
    for (int jt2 = 0; jt2 < 4; ++jt2)
#pragma unroll
      for (int r = 0; r < 4; ++r) {
        const size_t row = (size_t)(b * 4096 + m0 + mi * 16 + lg * 4 + r);
        O[row * 1024 + h * 64 + jt2 * 16 + lr] = o[jt2][r] * rs[r];
      }
  }
}

// ---------------------------------------------------------------------------
extern "C" void kernel_launch(void* const* d_in, const int* in_sizes, int n_in,
                              void* d_out, int out_size, void* d_ws, size_t ws_size,
                              hipStream_t stream) {
  (void)in_sizes; (void)n_in; (void)out_size; (void)ws_size;
  const float* x  = (const float*)d_in[0];
  const float* Wq = (const float*)d_in[1];
  const float* Wk = (const float*)d_in[2];
  const float* Wv = (const float*)d_in[3];
  const float* pk = (const float*)d_in[4];
  const float* pv = (const float*)d_in[5];
  float* out = (float*)d_out;

  // ws layout (f16 halfwords), total ~52.4 MB. Qh region doubles as f32
  // partials (32 MB) for stage1; gemm_q overwrites it after the reduce.
  // Xf16 + XT (33.5 MB each = 67.1 MB) live in d_out, which attn_k fully
  // overwrites at the end (all stream-ordered).
  __fp16* Qh  = (__fp16*)d_ws;                       // 16384*1024 f16
  __fp16* WqT = Qh  + (size_t)16384 * 1024;          // 1024*1024 each
  __fp16* WkT = WqT + (size_t)1024 * 1024;
  __fp16* WvT = WkT + (size_t)1024 * 1024;
  __fp16* pkT = WvT + (size_t)1024 * 1024;           // 256*4096 each
  __fp16* pvT = pkT + (size_t)256 * 4096;
  __fp16* Xk  = pvT + (size_t)256 * 4096;            // 4*256*1024 each
  __fp16* Xv  = Xk  + (size_t)4 * 256 * 1024;
  __fp16* Kp  = Xv  + (size_t)4 * 256 * 1024;
  __fp16* Vpt = Kp  + (size_t)4 * 256 * 1024;
  float* Pk = (float*)d_ws;                          // 16*256*1024 f32 each
  float* Pv = Pk + (size_t)16 * 256 * 1024;
  __fp16* Xf16 = (__fp16*)d_out;                     // 4*4096*1024 f16
  __fp16* XT   = Xf16 + (size_t)4 * 4096 * 1024;     // 4*1024*4096 f16

  const dim3 bb(256);

  // 0. one-time transposes/conversions
  xprep<<<dim3(128, 16, 4), bb, 0, stream>>>(x, Xf16, XT);
  tr_cvt<<<dim3(32, 32), bb, 0, stream>>>(Wq, WqT, 1024, 1024);
  tr_cvt<<<dim3(32, 32), bb, 0, stream>>>(Wk, WkT, 1024, 1024);
  tr_cvt<<<dim3(32, 32), bb, 0, stream>>>(Wv, WvT, 1024, 1024);
  tr_cvt<<<dim3(8, 128), bb, 0, stream>>>(pk, pkT, 4096, 256);
  tr_cvt<<<dim3(8, 128), bb, 0, stream>>>(pv, pvT, 4096, 256);

  // 1. split-K low-rank projections of X^T + reduce
  stage1_partial<<<dim3(1024), bb, 0, stream>>>(pkT, pvT, XT, Pk, Pv);
  stage1_reduce<<<dim3(1024), bb, 0, stream>>>(Pk, Pv, Xk, Xv);

  // 2. Kp = Xk . Wk ; VpT = (Xv . Wv)^T
  bt64<<<dim3(4, 16, 4), bb, 0, stream>>>(Xk, 256LL * 1024, WkT, 0LL,
                                          Kp, 1024, 256LL * 1024);
  bt64<<<dim3(16, 4, 4), bb, 0, stream>>>(WvT, 0LL, Xv, 256LL * 1024,
                                          Vpt, 256, 1024LL * 256);

  // 3. Q projection (pure f16, BK=64; overwrites partials region)
  gemm_q<<<dim3(1024), bb, 0, stream>>>(Xf16, WqT, Qh);

  // 4. attention (overwrites Xf16/XT = d_out)
  attn_k<<<dim3(2048), bb, 0, stream>>>(Qh, Kp, Vpt, out);
}